// Round 4
// baseline (156.658 us; speedup 1.0000x reference)
//
#include <hip/hip_runtime.h>
#include <hip/hip_bf16.h>

#define B_SZ 16384
#define E_SZ 128
#define H_SZ 256
#define A_SZ 20
#define K_SZ 384           // H + E
#define BH   (B_SZ * H_SZ) // 4194304

typedef __attribute__((ext_vector_type(8))) short  short8v;
typedef __attribute__((ext_vector_type(4))) float  f32x4;
typedef __attribute__((ext_vector_type(2))) float  f32x2;
typedef __attribute__((ext_vector_type(4))) unsigned short ushort4v;
typedef __attribute__((ext_vector_type(2))) unsigned short ushort2v;

__device__ __forceinline__ unsigned short f2bf(float f) {
    union { float f; unsigned u; } v; v.f = f;
    unsigned r = v.u + 0x7fffu + ((v.u >> 16) & 1u);   // RNE
    return (unsigned short)(r >> 16);
}

__device__ __forceinline__ float wsum(float v) {
    #pragma unroll
    for (int off = 32; off > 0; off >>= 1) v += __shfl_xor(v, off, 64);
    return v;
}

__device__ __forceinline__ float sigm(float x) { return 1.0f / (1.0f + __expf(-x)); }

struct Ptr8 { const float* p[8]; };

// ---------------- Kernel 1: attention + bf16 pack of A1=[h|x1], A2=[h|x2m] ----
// (R1 design: 4096 blocks x 256 thr -> high occupancy for the 168MB x2 read)
__global__ __launch_bounds__(256) void attn_pack(
    const float* __restrict__ x1, const float* __restrict__ x2,
    const float* __restrict__ h,  const float* __restrict__ wa,
    unsigned short* __restrict__ A1, unsigned short* __restrict__ A2)
{
    const int row  = blockIdx.x * 4 + (threadIdx.x >> 6);
    const int lane = threadIdx.x & 63;

    const f32x4 hv   = *(const f32x4*)(h  + (size_t)row * H_SZ + 4 * lane);
    const f32x2 x1v  = *(const f32x2*)(x1 + (size_t)row * E_SZ + 2 * lane);
    const f32x4 wah  = *(const f32x4*)(wa + 4 * lane);
    const f32x2 wax1 = *(const f32x2*)(wa + H_SZ + 2 * lane);
    const f32x2 wax2 = *(const f32x2*)(wa + H_SZ + E_SZ + 2 * lane);

    float base = hv.x * wah.x + hv.y * wah.y + hv.z * wah.z + hv.w * wah.w
               + x1v.x * wax1.x + x1v.y * wax1.y;

    f32x2 xv[A_SZ];
    float sp[A_SZ];
    const float* x2r = x2 + (size_t)row * A_SZ * E_SZ;
    #pragma unroll
    for (int a = 0; a < A_SZ; ++a) {
        xv[a] = *(const f32x2*)(x2r + a * E_SZ + 2 * lane);
        sp[a] = xv[a].x * wax2.x + xv[a].y * wax2.y;
    }

    base = wsum(base);
    #pragma unroll
    for (int a = 0; a < A_SZ; ++a) sp[a] = wsum(sp[a]) + base;

    float mx = sp[0];
    #pragma unroll
    for (int a = 1; a < A_SZ; ++a) mx = fmaxf(mx, sp[a]);
    float s = 0.0f;
    #pragma unroll
    for (int a = 0; a < A_SZ; ++a) { sp[a] = __expf(sp[a] - mx); s += sp[a]; }
    const float inv = 1.0f / s;

    float m0 = 0.0f, m1 = 0.0f;
    #pragma unroll
    for (int a = 0; a < A_SZ; ++a) { m0 += sp[a] * xv[a].x; m1 += sp[a] * xv[a].y; }
    m0 *= inv; m1 *= inv;

    ushort4v hb;
    hb.x = f2bf(hv.x); hb.y = f2bf(hv.y); hb.z = f2bf(hv.z); hb.w = f2bf(hv.w);
    *(ushort4v*)(A1 + (size_t)row * K_SZ + 4 * lane) = hb;
    *(ushort4v*)(A2 + (size_t)row * K_SZ + 4 * lane) = hb;
    ushort2v x1b; x1b.x = f2bf(x1v.x); x1b.y = f2bf(x1v.y);
    *(ushort2v*)(A1 + (size_t)row * K_SZ + H_SZ + 2 * lane) = x1b;
    ushort2v mb; mb.x = f2bf(m0); mb.y = f2bf(m1);
    *(ushort2v*)(A2 + (size_t)row * K_SZ + H_SZ + 2 * lane) = mb;
}

// ---------------- Kernel 2: weight transpose+pack: Wt[g][n][k] bf16 ----------
__global__ __launch_bounds__(256) void pack_w(Ptr8 ws, unsigned short* __restrict__ Wt)
{
    const int g = blockIdx.z, nt = blockIdx.y, kt = blockIdx.x;
    __shared__ float tile[64][65];
    const float* W = ws.p[g];
    const int c = threadIdx.x & 63, r0 = threadIdx.x >> 6;
    #pragma unroll
    for (int i = 0; i < 16; ++i) {
        int r = r0 + 4 * i;
        tile[r][c] = W[(size_t)(kt * 64 + r) * H_SZ + nt * 64 + c];
    }
    __syncthreads();
    #pragma unroll
    for (int i = 0; i < 16; ++i) {
        int rr = r0 + 4 * i;
        Wt[(size_t)g * 256 * 384 + (size_t)(nt * 64 + rr) * K_SZ + kt * 64 + c] =
            f2bf(tile[c][rr]);
    }
}

// ---------------- Kernel 3: 8-gate GEMM + LSTM epilogue, v2 -----------------
// Grid 512 x 512thr. Block = 32 rows x 256 cols, 8 waves (wave w = gate w;
// w<4: cell1/A1, w>=4: cell2/A2). A1/A2 staged ONCE (full K=384) into LDS via
// global_load_lds (linear dest + pre-swizzled source + swizzled ds_read);
// B-frags register-double-buffered to hide L2 latency. 80KB LDS -> 2 blk/CU.
__global__ __launch_bounds__(512, 4) void gemm_ep(
    const unsigned short* __restrict__ A1, const unsigned short* __restrict__ A2,
    const unsigned short* __restrict__ Wt, Ptr8 bias,
    const float* __restrict__ c1, const float* __restrict__ c2,
    float* __restrict__ out)
{
    __shared__ char smem[81920];   // A1 tile 24576 | A2 tile 24576 | glf 32768
    const int tid = threadIdx.x, w = tid >> 6, lane = tid & 63;
    const int row0 = blockIdx.x * 32;
    const int fr = lane & 15, hi = lane >> 4;

    // ---- stage both A tiles, full K, one shot ----
    #pragma unroll
    for (int cell = 0; cell < 2; ++cell) {
        const unsigned short* Ap = cell ? A2 : A1;
        #pragma unroll
        for (int i = 0; i < 3; ++i) {
            const int o = i * 8192 + w * 1024 + lane * 16;  // linear byte off in tile
            const int R = o / 768;                          // tile row
            const int sl = (o - R * 768) >> 4;              // linear 16B slot
            const int s = sl ^ (R & 7);                     // pre-swizzled source slot
            const unsigned short* src = Ap + (size_t)(row0 + R) * K_SZ + s * 8;
            char* dst = smem + cell * 24576 + i * 8192 + w * 1024; // wave-uniform
            __builtin_amdgcn_global_load_lds(
                (const __attribute__((address_space(1))) unsigned int*)src,
                (__attribute__((address_space(3))) unsigned int*)dst, 16, 0, 0);
        }
    }

    const unsigned short* Wg = Wt + (size_t)w * 256 * 384;
    const char* tb = smem + (w >> 2) * 24576;
    float* glf = (float*)(smem + 49152);
    const int erow = tid >> 5;            // 0..15
    const int ecol = (tid & 31) * 2;      // 0..62
    const int eswz = (erow & 7) << 2;

    __syncthreads();   // drains staging

    for (int nc = 0; nc < 4; ++nc) {
        const int col0 = nc * 64;

        f32x4 acc[2][4];
        #pragma unroll
        for (int mi = 0; mi < 2; ++mi)
            #pragma unroll
            for (int ni = 0; ni < 4; ++ni) acc[mi][ni] = (f32x4){0.f, 0.f, 0.f, 0.f};

        const unsigned short* bb = Wg + (size_t)(col0 + fr) * K_SZ + hi * 8;

        short8v bcur[4];
        #pragma unroll
        for (int ni = 0; ni < 4; ++ni)
            bcur[ni] = *(const short8v*)(bb + ni * 16 * K_SZ);

        #pragma unroll
        for (int kk = 0; kk < 12; ++kk) {
            short8v bnxt[4];
            if (kk < 11) {
                #pragma unroll
                for (int ni = 0; ni < 4; ++ni)
                    bnxt[ni] = *(const short8v*)(bb + ni * 16 * K_SZ + (kk + 1) * 32);
            }
            short8v afr[2];
            #pragma unroll
            for (int mi = 0; mi < 2; ++mi) {
                const int R = mi * 16 + fr;
                const int s = ((kk << 2) + hi) ^ (R & 7);
                afr[mi] = *(const short8v*)(tb + R * 768 + s * 16);
            }
            #pragma unroll
            for (int mi = 0; mi < 2; ++mi)
                #pragma unroll
                for (int ni = 0; ni < 4; ++ni)
                    acc[mi][ni] = __builtin_amdgcn_mfma_f32_16x16x32_bf16(
                        afr[mi], bcur[ni], acc[mi][ni], 0, 0, 0);
            if (kk < 11) {
                #pragma unroll
                for (int ni = 0; ni < 4; ++ni) bcur[ni] = bnxt[ni];
            }
        }

        // ---- epilogue for this 64-col block ----
        const int col = col0 + ecol;
        f32x2 c1p[2], c2p[2], bia[8];
        #pragma unroll
        for (int sp = 0; sp < 2; ++sp) {
            const int b = row0 + sp * 16 + erow;
            c1p[sp] = *(const f32x2*)(c1 + (size_t)b * H_SZ + col);
            c2p[sp] = *(const f32x2*)(c2 + (size_t)b * H_SZ + col);
        }
        #pragma unroll
        for (int g = 0; g < 8; ++g)
            bia[g] = *(const f32x2*)(bias.p[g] + col);

        #pragma unroll
        for (int sp = 0; sp < 2; ++sp) {
            __syncthreads();
            #pragma unroll
            for (int ni = 0; ni < 4; ++ni)
                #pragma unroll
                for (int j = 0; j < 4; ++j) {
                    const int rl = hi * 4 + j;
                    glf[(w * 16 + rl) * 64 + ((ni * 16 + fr) ^ ((rl & 7) << 2))] =
                        acc[sp][ni][j];
                }
            __syncthreads();

            f32x2 G[8];
            #pragma unroll
            for (int g = 0; g < 8; ++g)
                G[g] = *(const f32x2*)(glf + (g * 16 + erow) * 64 + (ecol ^ eswz));

            const int b = row0 + sp * 16 + erow;
            f32x2 hn, c1o, c2o;
            #pragma unroll
            for (int j = 0; j < 2; ++j) {
                float f1  = sigm(G[0][j] + bia[0][j]);
                float i1  = sigm(G[1][j] + bia[1][j]);
                float c1t = tanhf(G[2][j] + bia[2][j]);
                float o1  = G[3][j] + bia[3][j];
                float f2  = sigm(G[4][j] + bia[4][j]);
                float i2  = sigm(G[5][j] + bia[5][j]);
                float c2t = tanhf(G[6][j] + bia[6][j]);
                float o2  = G[7][j] + bia[7][j];
                float c1n = f1 * c1p[sp][j] + i1 * c1t;
                float c2n = f2 * c2p[sp][j] + i2 * c2t;
                float mo  = fmaxf(o1, o2);
                float e1  = __expf(o1 - mo), e2 = __expf(o2 - mo);
                float g0  = e1 / (e1 + e2);
                hn[j]  = g0 * tanhf(c1n) + (1.0f - g0) * tanhf(c2n);
                c1o[j] = c1n; c2o[j] = c2n;
            }
            const size_t o0 = (size_t)b * H_SZ + col;
            *(f32x2*)(out + o0)          = hn;
            *(f32x2*)(out + BH + o0)     = c1o;
            *(f32x2*)(out + 2 * BH + o0) = c2o;
        }
    }
}

// ---------------- host ----------------
extern "C" void kernel_launch(void* const* d_in, const int* in_sizes, int n_in,
                              void* d_out, int out_size, void* d_ws, size_t ws_size,
                              hipStream_t stream)
{
    const float* x1 = (const float*)d_in[0];
    const float* x2 = (const float*)d_in[1];
    const float* h  = (const float*)d_in[2];
    const float* c1 = (const float*)d_in[3];
    const float* c2 = (const float*)d_in[4];
    const float* wa = (const float*)d_in[21];

    // gate order: 0..3 = cell1 {f,i,c,o}; 4..7 = cell2 {f,i,c,o}
    Ptr8 wptr, bptr;
    wptr.p[0] = (const float*)d_in[5];  wptr.p[1] = (const float*)d_in[9];
    wptr.p[2] = (const float*)d_in[13]; wptr.p[3] = (const float*)d_in[17];
    wptr.p[4] = (const float*)d_in[6];  wptr.p[5] = (const float*)d_in[10];
    wptr.p[6] = (const float*)d_in[14]; wptr.p[7] = (const float*)d_in[18];
    bptr.p[0] = (const float*)d_in[7];  bptr.p[1] = (const float*)d_in[11];
    bptr.p[2] = (const float*)d_in[15]; bptr.p[3] = (const float*)d_in[19];
    bptr.p[4] = (const float*)d_in[8];  bptr.p[5] = (const float*)d_in[12];
    bptr.p[6] = (const float*)d_in[16]; bptr.p[7] = (const float*)d_in[20];

    char* ws = (char*)d_ws;
    unsigned short* A1 = (unsigned short*)(ws);              // 12.6 MB
    unsigned short* A2 = (unsigned short*)(ws + 12582912);   // 12.6 MB
    unsigned short* Wt = (unsigned short*)(ws + 25165824);   // 1.6 MB

    attn_pack<<<B_SZ / 4, 256, 0, stream>>>(x1, x2, h, wa, A1, A2);
    pack_w<<<dim3(6, 4, 8), 256, 0, stream>>>(wptr, Wt);
    gemm_ep<<<512, 512, 0, stream>>>(A1, A2, Wt, bptr, c1, c2, (float*)d_out);
}

// Round 5
// 108.144 us; speedup vs baseline: 1.4486x; 1.4486x over previous
//
#include <hip/hip_runtime.h>
#include <hip/hip_bf16.h>

#define B_SZ 16384
#define E_SZ 128
#define H_SZ 256
#define A_SZ 20
#define K_SZ 384           // H + E
#define BH   (B_SZ * H_SZ) // 4194304

typedef __attribute__((ext_vector_type(8))) short  short8v;
typedef __attribute__((ext_vector_type(4))) float  f32x4;
typedef __attribute__((ext_vector_type(2))) float  f32x2;
typedef __attribute__((ext_vector_type(4))) unsigned short ushort4v;
typedef __attribute__((ext_vector_type(2))) unsigned short ushort2v;

__device__ __forceinline__ unsigned short f2bf(float f) {
    union { float f; unsigned u; } v; v.f = f;
    unsigned r = v.u + 0x7fffu + ((v.u >> 16) & 1u);   // RNE
    return (unsigned short)(r >> 16);
}

__device__ __forceinline__ float wsum(float v) {
    #pragma unroll
    for (int off = 32; off > 0; off >>= 1) v += __shfl_xor(v, off, 64);
    return v;
}

__device__ __forceinline__ float sigm(float x) { return 1.0f / (1.0f + __expf(-x)); }

struct Ptr8 { const float* p[8]; };

// ---------------- Kernel 1: attention + bf16 pack of A1=[h|x1], A2=[h|x2m] ----
__global__ __launch_bounds__(256) void attn_pack(
    const float* __restrict__ x1, const float* __restrict__ x2,
    const float* __restrict__ h,  const float* __restrict__ wa,
    unsigned short* __restrict__ A1, unsigned short* __restrict__ A2)
{
    const int row  = blockIdx.x * 4 + (threadIdx.x >> 6);
    const int lane = threadIdx.x & 63;

    const f32x4 hv   = *(const f32x4*)(h  + (size_t)row * H_SZ + 4 * lane);
    const f32x2 x1v  = *(const f32x2*)(x1 + (size_t)row * E_SZ + 2 * lane);
    const f32x4 wah  = *(const f32x4*)(wa + 4 * lane);
    const f32x2 wax1 = *(const f32x2*)(wa + H_SZ + 2 * lane);
    const f32x2 wax2 = *(const f32x2*)(wa + H_SZ + E_SZ + 2 * lane);

    float base = hv.x * wah.x + hv.y * wah.y + hv.z * wah.z + hv.w * wah.w
               + x1v.x * wax1.x + x1v.y * wax1.y;

    f32x2 xv[A_SZ];
    float sp[A_SZ];
    const float* x2r = x2 + (size_t)row * A_SZ * E_SZ;
    #pragma unroll
    for (int a = 0; a < A_SZ; ++a) {
        xv[a] = *(const f32x2*)(x2r + a * E_SZ + 2 * lane);
        sp[a] = xv[a].x * wax2.x + xv[a].y * wax2.y;
    }

    base = wsum(base);
    #pragma unroll
    for (int a = 0; a < A_SZ; ++a) sp[a] = wsum(sp[a]) + base;

    float mx = sp[0];
    #pragma unroll
    for (int a = 1; a < A_SZ; ++a) mx = fmaxf(mx, sp[a]);
    float s = 0.0f;
    #pragma unroll
    for (int a = 0; a < A_SZ; ++a) { sp[a] = __expf(sp[a] - mx); s += sp[a]; }
    const float inv = 1.0f / s;

    float m0 = 0.0f, m1 = 0.0f;
    #pragma unroll
    for (int a = 0; a < A_SZ; ++a) { m0 += sp[a] * xv[a].x; m1 += sp[a] * xv[a].y; }
    m0 *= inv; m1 *= inv;

    ushort4v hb;
    hb.x = f2bf(hv.x); hb.y = f2bf(hv.y); hb.z = f2bf(hv.z); hb.w = f2bf(hv.w);
    *(ushort4v*)(A1 + (size_t)row * K_SZ + 4 * lane) = hb;
    *(ushort4v*)(A2 + (size_t)row * K_SZ + 4 * lane) = hb;
    ushort2v x1b; x1b.x = f2bf(x1v.x); x1b.y = f2bf(x1v.y);
    *(ushort2v*)(A1 + (size_t)row * K_SZ + H_SZ + 2 * lane) = x1b;
    ushort2v mb; mb.x = f2bf(m0); mb.y = f2bf(m1);
    *(ushort2v*)(A2 + (size_t)row * K_SZ + H_SZ + 2 * lane) = mb;
}

// ---------------- Kernel 2: weight pack: Wt2[nn][k], nn = hcblk*256+g*32+hcin
__global__ __launch_bounds__(256) void pack_w(Ptr8 ws, unsigned short* __restrict__ Wt)
{
    const int g = blockIdx.z, nt = blockIdx.y, kt = blockIdx.x;
    __shared__ float tile[64][65];
    const float* W = ws.p[g];
    const int c = threadIdx.x & 63, r0 = threadIdx.x >> 6;
    #pragma unroll
    for (int i = 0; i < 16; ++i) {
        int r = r0 + 4 * i;
        tile[r][c] = W[(size_t)(kt * 64 + r) * H_SZ + nt * 64 + c];
    }
    __syncthreads();
    #pragma unroll
    for (int i = 0; i < 16; ++i) {
        int rr = r0 + 4 * i;
        const int hcol = nt * 64 + rr;
        const int nn = ((hcol >> 5) << 8) + g * 32 + (hcol & 31);
        Wt[(size_t)nn * K_SZ + kt * 64 + c] = f2bf(tile[c][rr]);
    }
}

// ---------------- Kernel 3: m97-structure GEMM + fused LSTM epilogue --------
// Grid 1024 x 512thr. Block = 128 rows x 256 cols (8 gates x 32 hcols).
// 8 waves 2Mx4N, wave tile 64x64 (acc[4][4]); wN<2 -> cell1/A1, wN>=2 -> A2.
// LDS: dbuf x [A1 16K | A2 16K | B 32K] = 128KB, glds staged, XOR-swizzled.
__global__ __launch_bounds__(512, 1) void gemm_ep(
    const unsigned short* __restrict__ A1, const unsigned short* __restrict__ A2,
    const unsigned short* __restrict__ Wt, Ptr8 bias,
    const float* __restrict__ c1, const float* __restrict__ c2,
    float* __restrict__ out)
{
    __shared__ char smem[131072];
    const int tid = threadIdx.x, w = tid >> 6, lane = tid & 63;
    const int d = blockIdx.x;
    // XCD-aware: XCD x (= d&7) owns rbs x*16..x*16+15, all 8 hcblks -> A-panel
    // L2-resident per XCD.  Bijective for d in [0,1024).
    const int rb  = (d & 7) * 16 + (d >> 6);
    const int hcb = (d >> 3) & 7;
    const int row0 = rb * 128, hcol0 = hcb * 32;
    const int fr = lane & 15, hi = lane >> 4;
    const int wM = w >> 2, wN = w & 3;

    const unsigned short* Bpan = Wt + (size_t)hcb * 256 * K_SZ;
    const int Rl = tid >> 3, sl = tid & 7;   // staging: 8 lanes per 128B row

    auto stage = [&](int buf, int ks) {
        const int bufb = buf * 65536;
        #pragma unroll
        for (int i = 0; i < 2; ++i) {            // A1 panel: 128 rows x 64 k
            const int R = i * 64 + Rl;
            const unsigned short* src =
                A1 + (size_t)(row0 + R) * K_SZ + ks * 64 + ((sl ^ (R & 7)) << 3);
            __builtin_amdgcn_global_load_lds(
                (const __attribute__((address_space(1))) unsigned int*)src,
                (__attribute__((address_space(3))) unsigned int*)
                    (smem + bufb + i * 8192 + w * 1024), 16, 0, 0);
        }
        #pragma unroll
        for (int i = 0; i < 2; ++i) {            // A2 panel
            const int R = i * 64 + Rl;
            const unsigned short* src =
                A2 + (size_t)(row0 + R) * K_SZ + ks * 64 + ((sl ^ (R & 7)) << 3);
            __builtin_amdgcn_global_load_lds(
                (const __attribute__((address_space(1))) unsigned int*)src,
                (__attribute__((address_space(3))) unsigned int*)
                    (smem + bufb + 16384 + i * 8192 + w * 1024), 16, 0, 0);
        }
        #pragma unroll
        for (int j = 0; j < 4; ++j) {            // B panel: 256 cols x 64 k
            const int C = j * 64 + Rl;
            const unsigned short* src =
                Bpan + (size_t)C * K_SZ + ks * 64 + ((sl ^ (C & 7)) << 3);
            __builtin_amdgcn_global_load_lds(
                (const __attribute__((address_space(1))) unsigned int*)src,
                (__attribute__((address_space(3))) unsigned int*)
                    (smem + bufb + 32768 + j * 8192 + w * 1024), 16, 0, 0);
        }
    };

    f32x4 acc[4][4];
    #pragma unroll
    for (int mi = 0; mi < 4; ++mi)
        #pragma unroll
        for (int ni = 0; ni < 4; ++ni) acc[mi][ni] = (f32x4){0.f, 0.f, 0.f, 0.f};

    const int apan = (wN >= 2) ? 16384 : 0;

    stage(0, 0);
    int buf = 0;
    for (int ks = 0; ks < 6; ++ks) {
        __syncthreads();                         // staging of ks complete
        if (ks < 5) stage(buf ^ 1, ks + 1);      // prefetch flies under compute
        const char* bb = smem + buf * 65536;
        #pragma unroll
        for (int kk = 0; kk < 2; ++kk) {
            short8v af[4], bf[4];
            #pragma unroll
            for (int mi = 0; mi < 4; ++mi) {
                const int R = wM * 64 + mi * 16 + fr;
                af[mi] = *(const short8v*)(bb + apan + R * 128 +
                                           ((((kk << 2) + hi) ^ (R & 7)) << 4));
            }
            #pragma unroll
            for (int ni = 0; ni < 4; ++ni) {
                const int C = wN * 64 + ni * 16 + fr;
                bf[ni] = *(const short8v*)(bb + 32768 + C * 128 +
                                           ((((kk << 2) + hi) ^ (C & 7)) << 4));
            }
            #pragma unroll
            for (int mi = 0; mi < 4; ++mi)
                #pragma unroll
                for (int ni = 0; ni < 4; ++ni)
                    acc[mi][ni] = __builtin_amdgcn_mfma_f32_16x16x32_bf16(
                        af[mi], bf[ni], acc[mi][ni], 0, 0, 0);
        }
        buf ^= 1;
    }

    // ---- epilogue: exchange all 8 gates through LDS (reuse both buffers) ---
    const int hcin = tid & 31, rsl = tid >> 5;
    float c1p[8], c2p[8], bia[8];
    #pragma unroll
    for (int rr = 0; rr < 8; ++rr) {
        const int R = rsl * 8 + rr;
        c1p[rr] = c1[(size_t)(row0 + R) * H_SZ + hcol0 + hcin];
        c2p[rr] = c2[(size_t)(row0 + R) * H_SZ + hcol0 + hcin];
    }
    #pragma unroll
    for (int g = 0; g < 8; ++g) bia[g] = bias.p[g][hcol0 + hcin];

    __syncthreads();
    float* gf = (float*)smem;
    #pragma unroll
    for (int mi = 0; mi < 4; ++mi)
        #pragma unroll
        for (int ni = 0; ni < 4; ++ni)
            #pragma unroll
            for (int j = 0; j < 4; ++j) {
                const int R  = wM * 64 + mi * 16 + hi * 4 + j;
                const int g  = wN * 2 + (ni >> 1);
                const int hc = (ni & 1) * 16 + fr;
                const int hcr = (hc + ((R >> 2) & 3) * 8) & 31;  // bank rotation
                gf[g * 4096 + R * 32 + hcr] = acc[mi][ni][j];
            }
    __syncthreads();

    #pragma unroll
    for (int rr = 0; rr < 8; ++rr) {
        const int R = rsl * 8 + rr;
        const int hcr = (hcin + ((R >> 2) & 3) * 8) & 31;
        float G[8];
        #pragma unroll
        for (int g = 0; g < 8; ++g) G[g] = gf[g * 4096 + R * 32 + hcr] + bia[g];

        const float f1  = sigm(G[0]);
        const float i1  = sigm(G[1]);
        const float c1t = tanhf(G[2]);
        const float o1  = G[3];
        const float f2  = sigm(G[4]);
        const float i2  = sigm(G[5]);
        const float c2t = tanhf(G[6]);
        const float o2  = G[7];
        const float c1n = f1 * c1p[rr] + i1 * c1t;
        const float c2n = f2 * c2p[rr] + i2 * c2t;
        const float mo  = fmaxf(o1, o2);
        const float e1  = __expf(o1 - mo), e2 = __expf(o2 - mo);
        const float g0  = e1 / (e1 + e2);
        const float hn  = g0 * tanhf(c1n) + (1.0f - g0) * tanhf(c2n);

        const size_t o0 = (size_t)(row0 + R) * H_SZ + hcol0 + hcin;
        out[o0]          = hn;
        out[BH + o0]     = c1n;
        out[2 * BH + o0] = c2n;
    }
}

// ---------------- host ----------------
extern "C" void kernel_launch(void* const* d_in, const int* in_sizes, int n_in,
                              void* d_out, int out_size, void* d_ws, size_t ws_size,
                              hipStream_t stream)
{
    const float* x1 = (const float*)d_in[0];
    const float* x2 = (const float*)d_in[1];
    const float* h  = (const float*)d_in[2];
    const float* c1 = (const float*)d_in[3];
    const float* c2 = (const float*)d_in[4];
    const float* wa = (const float*)d_in[21];

    // gate order: 0..3 = cell1 {f,i,c,o}; 4..7 = cell2 {f,i,c,o}
    Ptr8 wptr, bptr;
    wptr.p[0] = (const float*)d_in[5];  wptr.p[1] = (const float*)d_in[9];
    wptr.p[2] = (const float*)d_in[13]; wptr.p[3] = (const float*)d_in[17];
    wptr.p[4] = (const float*)d_in[6];  wptr.p[5] = (const float*)d_in[10];
    wptr.p[6] = (const float*)d_in[14]; wptr.p[7] = (const float*)d_in[18];
    bptr.p[0] = (const float*)d_in[7];  bptr.p[1] = (const float*)d_in[11];
    bptr.p[2] = (const float*)d_in[15]; bptr.p[3] = (const float*)d_in[19];
    bptr.p[4] = (const float*)d_in[8];  bptr.p[5] = (const float*)d_in[12];
    bptr.p[6] = (const float*)d_in[16]; bptr.p[7] = (const float*)d_in[20];

    char* ws = (char*)d_ws;
    unsigned short* A1 = (unsigned short*)(ws);              // 12.6 MB
    unsigned short* A2 = (unsigned short*)(ws + 12582912);   // 12.6 MB
    unsigned short* Wt = (unsigned short*)(ws + 25165824);   // 1.6 MB

    pack_w<<<dim3(6, 4, 8), 256, 0, stream>>>(wptr, Wt);
    attn_pack<<<B_SZ / 4, 256, 0, stream>>>(x1, x2, h, wa, A1, A2);
    gemm_ep<<<1024, 512, 0, stream>>>(A1, A2, Wt, bptr, c1, c2, (float*)d_out);
}